// Round 1
// baseline (350.535 us; speedup 1.0000x reference)
//
#include <hip/hip_runtime.h>

// Cost-volume / correlation layer, fp32.
// out[b, (dy*9+dx), h, w] = (1/C) * sum_c first[b,c,h,w] * second[b,c,h+dy-4,w+dx-4]
// (zero outside bounds).  B=8, C=128, H=W=128, search_range=4 -> 81 offsets.
//
// Round-1 design: no LDS; register blocking RW=4 pixels/thread along w;
// dy split into 3 groups of 3 across gridDim.y so accumulators = 3*9*4 = 108
// VGPRs.  Per channel: 1 float4 load of first + 3 rows x 3 float4 of second
// (halo overlap served by L1/L2), then 108 FMAs.

constexpr int B = 8, C = 128, H = 128, W = 128;
constexpr int RNG = 4, MO = 9;   // search range, max_offset = 2*RNG+1
constexpr int DYG = 3;           // dy values per block
constexpr int RW  = 4;           // pixels per thread along w
constexpr int TY  = 8;           // pixel rows per block

__global__ __launch_bounds__(256) void corr_kernel(
    const float* __restrict__ first,
    const float* __restrict__ second,
    float* __restrict__ out)
{
    const int tx  = threadIdx.x;           // 0..31
    const int ty  = threadIdx.y;           // 0..7
    const int h   = blockIdx.x * TY + ty;  // 0..127
    const int dy0 = blockIdx.y * DYG;      // 0,3,6
    const int b   = blockIdx.z;
    const int w0  = tx * RW;               // 0..124

    float acc[DYG][MO][RW];
#pragma unroll
    for (int j = 0; j < DYG; ++j)
#pragma unroll
        for (int dx = 0; dx < MO; ++dx)
#pragma unroll
            for (int p = 0; p < RW; ++p) acc[j][dx][p] = 0.0f;

    const size_t HW = (size_t)H * W;
    const float* fptr = first  + (size_t)b * C * HW + (size_t)h * W + w0;
    const float* simg = second + (size_t)b * C * HW;

    // Row validity per dy (depends only on h, dy).
    int  sr[DYG];
    bool rv[DYG];
#pragma unroll
    for (int j = 0; j < DYG; ++j) {
        sr[j] = h + dy0 + j - RNG;
        rv[j] = (sr[j] >= 0) && (sr[j] < H);
    }

    // Column edge handling: only tx==0 (cols -4..-1) and tx==31 (cols 128..131)
    // have out-of-range columns.  Load from clamped addresses, zero afterwards.
    const bool ledge = (tx == 0);
    const bool redge = (tx == 31);
    const int off0 = ledge ? 0       : (w0 - 4);
    const int off2 = redge ? (W - 8) : (w0 + 4);

    for (int c = 0; c < C; ++c) {
        float4 fv4 = *(const float4*)(fptr + (size_t)c * HW);
        float fv[RW] = {fv4.x, fv4.y, fv4.z, fv4.w};
#pragma unroll
        for (int j = 0; j < DYG; ++j) {
            if (!rv[j]) continue;   // contribution is zero (padded rows)
            const float* srow = simg + (size_t)c * HW + (size_t)sr[j] * W;
            float4 a0 = *(const float4*)(srow + off0);
            float4 a1 = *(const float4*)(srow + w0);
            float4 a2 = *(const float4*)(srow + off2);
            if (ledge) a0 = make_float4(0.f, 0.f, 0.f, 0.f);
            if (redge) a2 = make_float4(0.f, 0.f, 0.f, 0.f);
            float s[12] = {a0.x, a0.y, a0.z, a0.w,
                           a1.x, a1.y, a1.z, a1.w,
                           a2.x, a2.y, a2.z, a2.w};
#pragma unroll
            for (int dx = 0; dx < MO; ++dx)
#pragma unroll
                for (int p = 0; p < RW; ++p)
                    acc[j][dx][p] += fv[p] * s[p + dx];
        }
    }

    const float inv = 1.0f / (float)C;
#pragma unroll
    for (int j = 0; j < DYG; ++j) {
        const int obase = (dy0 + j) * MO;
#pragma unroll
        for (int dx = 0; dx < MO; ++dx) {
            float4 v = make_float4(acc[j][dx][0] * inv,
                                   acc[j][dx][1] * inv,
                                   acc[j][dx][2] * inv,
                                   acc[j][dx][3] * inv);
            *(float4*)(out + ((size_t)b * (MO * MO) + obase + dx) * HW
                           + (size_t)h * W + w0) = v;
        }
    }
}

extern "C" void kernel_launch(void* const* d_in, const int* in_sizes, int n_in,
                              void* d_out, int out_size, void* d_ws, size_t ws_size,
                              hipStream_t stream) {
    const float* first  = (const float*)d_in[0];
    const float* second = (const float*)d_in[1];
    float* out = (float*)d_out;

    dim3 grid(H / TY, MO / DYG, B);   // (16, 3, 8) = 384 blocks
    dim3 block(32, TY);               // 256 threads
    corr_kernel<<<grid, block, 0, stream>>>(first, second, out);
}

// Round 2
// 230.099 us; speedup vs baseline: 1.5234x; 1.5234x over previous
//
#include <hip/hip_runtime.h>

// Cost-volume / correlation layer, fp32.
// out[b, dy*9+dx, h, w] = (1/C) * sum_c first[b,c,h,w] * second[b,c,h+dy-4,w+dx-4]
// (zero outside bounds).  B=8, C=128, H=W=128, search_range=4 -> 81 offsets.
//
// Round-2 design: DYG=1 (one dy per block) so accumulators = 9*4 = 36 VGPRs
// (R1's 108-float acc array spilled: VGPR_Count=76 < 108). Grid 3x larger
// (1152 blocks -> ~18 waves/CU vs R1's 6) to hide L1/L2 latency.
// Per channel iteration: 1 float4 of first + 3 float4 of second, 36 FMAs.

constexpr int B = 8, C = 128, H = 128, W = 128;
constexpr int RNG = 4, MO = 9;   // search range, max_offset = 2*RNG+1
constexpr int RW  = 4;           // pixels per thread along w
constexpr int TY  = 8;           // pixel rows per block

__global__ __launch_bounds__(256, 4) void corr_kernel(
    const float* __restrict__ first,
    const float* __restrict__ second,
    float* __restrict__ out)
{
    const int tx = threadIdx.x;           // 0..31
    const int ty = threadIdx.y;           // 0..7
    const int h  = blockIdx.x * TY + ty;  // 0..127
    const int dy = blockIdx.y;            // 0..8
    const int b  = blockIdx.z;
    const int w0 = tx * RW;               // 0..124

    float acc[MO][RW];
#pragma unroll
    for (int dx = 0; dx < MO; ++dx)
#pragma unroll
        for (int p = 0; p < RW; ++p) acc[dx][p] = 0.0f;

    const size_t HW = (size_t)H * W;
    const float* fptr = first  + (size_t)b * C * HW + (size_t)h * W + w0;

    const int  srow_i = h + dy - RNG;
    const bool rvalid = (srow_i >= 0) && (srow_i < H);
    // Clamp row for address safety; contribution discarded if !rvalid.
    const int  srow_c = srow_i < 0 ? 0 : (srow_i >= H ? H - 1 : srow_i);
    const float* sptr = second + (size_t)b * C * HW + (size_t)srow_c * W;

    // Column edges: tx==0 needs cols -4..-1 (zero), tx==31 needs 128..131.
    const bool ledge = (tx == 0);
    const bool redge = (tx == 31);
    const int off0 = ledge ? 0       : (w0 - 4);   // all 16B-aligned
    const int off2 = redge ? (W - 8) : (w0 + 4);

    if (rvalid) {
        for (int c = 0; c < C; ++c) {
            float4 fv4 = *(const float4*)(fptr + (size_t)c * HW);
            float fv[RW] = {fv4.x, fv4.y, fv4.z, fv4.w};
            const float* srow = sptr + (size_t)c * HW;
            float4 a0 = *(const float4*)(srow + off0);
            float4 a1 = *(const float4*)(srow + w0);
            float4 a2 = *(const float4*)(srow + off2);
            if (ledge) a0 = make_float4(0.f, 0.f, 0.f, 0.f);
            if (redge) a2 = make_float4(0.f, 0.f, 0.f, 0.f);
            float s[12] = {a0.x, a0.y, a0.z, a0.w,
                           a1.x, a1.y, a1.z, a1.w,
                           a2.x, a2.y, a2.z, a2.w};
#pragma unroll
            for (int dx = 0; dx < MO; ++dx)
#pragma unroll
                for (int p = 0; p < RW; ++p)
                    acc[dx][p] += fv[p] * s[p + dx];
        }
    }

    const float inv = 1.0f / (float)C;
    float* obase = out + ((size_t)b * (MO * MO) + (size_t)dy * MO) * HW
                       + (size_t)h * W + w0;
#pragma unroll
    for (int dx = 0; dx < MO; ++dx) {
        float4 v = make_float4(acc[dx][0] * inv, acc[dx][1] * inv,
                               acc[dx][2] * inv, acc[dx][3] * inv);
        *(float4*)(obase + (size_t)dx * HW) = v;
    }
}

extern "C" void kernel_launch(void* const* d_in, const int* in_sizes, int n_in,
                              void* d_out, int out_size, void* d_ws, size_t ws_size,
                              hipStream_t stream) {
    const float* first  = (const float*)d_in[0];
    const float* second = (const float*)d_in[1];
    float* out = (float*)d_out;

    dim3 grid(H / TY, MO, B);   // (16, 9, 8) = 1152 blocks
    dim3 block(32, TY);         // 256 threads
    corr_kernel<<<grid, block, 0, stream>>>(first, second, out);
}

// Round 3
// 227.340 us; speedup vs baseline: 1.5419x; 1.0121x over previous
//
#include <hip/hip_runtime.h>

// Cost-volume / correlation layer, fp32.
// out[b, dy*9+dx, h, w] = (1/C) * sum_c first[b,c,h,w] * second[b,c,h+dy-4,w+dx-4]
// (zero outside bounds).  B=8, C=128, H=W=128, search_range=4 -> 81 offsets.
//
// Round-3: R2 was latency-bound (VALU issue ~17us of 127us; VGPR=44 => no
// loads in flight across c-iterations; 4.5 waves/SIMD grid-limited).
// This round: explicit software pipeline, prefetch distance 1, unroll-by-2
// ping-pong register sets so iteration c's FMAs overlap c+1's loads.

constexpr int B = 8, C = 128, H = 128, W = 128;
constexpr int RNG = 4, MO = 9;   // search range, max_offset = 2*RNG+1
constexpr int RW  = 4;           // pixels per thread along w
constexpr int TY  = 8;           // pixel rows per block

__global__ __launch_bounds__(256) void corr_kernel(
    const float* __restrict__ first,
    const float* __restrict__ second,
    float* __restrict__ out)
{
    const int tx = threadIdx.x;           // 0..31
    const int ty = threadIdx.y;           // 0..7
    const int h  = blockIdx.x * TY + ty;  // 0..127
    const int dy = blockIdx.y;            // 0..8
    const int b  = blockIdx.z;
    const int w0 = tx * RW;               // 0..124

    float acc[MO][RW];
#pragma unroll
    for (int dx = 0; dx < MO; ++dx)
#pragma unroll
        for (int p = 0; p < RW; ++p) acc[dx][p] = 0.0f;

    const size_t HW = (size_t)H * W;
    const float* fptr = first + (size_t)b * C * HW + (size_t)h * W + w0;

    const int  srow_i = h + dy - RNG;
    const bool rvalid = (srow_i >= 0) && (srow_i < H);
    const int  srow_c = srow_i < 0 ? 0 : (srow_i >= H ? H - 1 : srow_i);
    const float* sptr = second + (size_t)b * C * HW + (size_t)srow_c * W;

    // Column edges: tx==0 needs cols -4..-1 (zero), tx==31 needs 128..131.
    const bool ledge = (tx == 0);
    const bool redge = (tx == 31);
    const int off0 = ledge ? 0       : (w0 - 4);   // all 16B-aligned
    const int off2 = redge ? (W - 8) : (w0 + 4);

    if (rvalid) {
        // ---- software pipeline: prefetch distance 1, ping-pong regs ----
        float4 fA, a0A, a1A, a2A, fB, a0B, a1B, a2B;

        // prologue: load c = 0 into set A
        fA  = *(const float4*)(fptr);
        a0A = *(const float4*)(sptr + off0);
        a1A = *(const float4*)(sptr + w0);
        a2A = *(const float4*)(sptr + off2);

#define PREFETCH(SET, cidx)                                                 \
        {                                                                   \
            const int   pc = ((cidx) < C) ? (cidx) : (C - 1);               \
            const size_t o = (size_t)pc * HW;                               \
            f##SET  = *(const float4*)(fptr + o);                           \
            a0##SET = *(const float4*)(sptr + o + off0);                    \
            a1##SET = *(const float4*)(sptr + o + w0);                      \
            a2##SET = *(const float4*)(sptr + o + off2);                    \
        }

#define COMPUTE(SET)                                                        \
        {                                                                   \
            float4 z0 = a0##SET, z2 = a2##SET;                              \
            if (ledge) z0 = make_float4(0.f, 0.f, 0.f, 0.f);                \
            if (redge) z2 = make_float4(0.f, 0.f, 0.f, 0.f);                \
            float fv[RW] = {f##SET.x, f##SET.y, f##SET.z, f##SET.w};        \
            float s[12]  = {z0.x, z0.y, z0.z, z0.w,                         \
                            a1##SET.x, a1##SET.y, a1##SET.z, a1##SET.w,     \
                            z2.x, z2.y, z2.z, z2.w};                        \
            _Pragma("unroll")                                               \
            for (int dx = 0; dx < MO; ++dx)                                 \
                _Pragma("unroll")                                           \
                for (int p = 0; p < RW; ++p)                                \
                    acc[dx][p] += fv[p] * s[p + dx];                        \
        }

        for (int c = 0; c < C; c += 2) {
            PREFETCH(B, c + 1)   // issue loads for c+1
            COMPUTE(A)           // FMAs for c (overlaps B's loads)
            PREFETCH(A, c + 2)   // issue loads for c+2
            COMPUTE(B)           // FMAs for c+1 (overlaps A's loads)
        }
#undef PREFETCH
#undef COMPUTE
    }

    const float inv = 1.0f / (float)C;
    float* obase = out + ((size_t)b * (MO * MO) + (size_t)dy * MO) * HW
                       + (size_t)h * W + w0;
#pragma unroll
    for (int dx = 0; dx < MO; ++dx) {
        float4 v = make_float4(acc[dx][0] * inv, acc[dx][1] * inv,
                               acc[dx][2] * inv, acc[dx][3] * inv);
        *(float4*)(obase + (size_t)dx * HW) = v;
    }
}

extern "C" void kernel_launch(void* const* d_in, const int* in_sizes, int n_in,
                              void* d_out, int out_size, void* d_ws, size_t ws_size,
                              hipStream_t stream) {
    const float* first  = (const float*)d_in[0];
    const float* second = (const float*)d_in[1];
    float* out = (float*)d_out;

    dim3 grid(H / TY, MO, B);   // (16, 9, 8) = 1152 blocks
    dim3 block(32, TY);         // 256 threads
    corr_kernel<<<grid, block, 0, stream>>>(first, second, out);
}